// Round 13
// baseline (379.945 us; speedup 1.0000x reference)
//
#include <hip/hip_runtime.h>
#include <hip/hip_bf16.h>
#include <math.h>

// ---------------------------------------------------------------------------
// GCN predictor: 2x GCNConv(relu) -> mean pool + global feats -> MLP head
// N=100K nodes, E=3.2M directed edges, H=64.
// R13: degree-sorted node order (counting sort, 3 tiny kernels) so the
// lockstep gather streams have equal lengths (kills ~20% max-len waste in
// l2fuse and ~70% per-lane divergence waste in agg5); l2fuse widened to
// 8 streams/wave (2x MLP) with W2 hoisted into 64 VGPRs.
// Carries R12's no-hot-atomics discipline (gf partials, RCOPY spread).
// ---------------------------------------------------------------------------

#define BUCKET 256
#define MAXB   512    // max buckets (needs n <= 131072)
#define NCHV   2048   // edge chunks
#define Q      8      // csr record slices per bucket
#define RCOPY  32     // spread copies for the mean-pool accumulator
#define DNB    256    // degree-sort blocks

// per-chunk bucket histogram: gcounts[chunk*NBK + bucket]
__global__ void k_hist(const int* __restrict__ dst, int E, int chunk,
                       int* __restrict__ gcounts, int NBK) {
    __shared__ int lcnt[MAXB];
    for (int i = threadIdx.x; i < NBK; i += blockDim.x) lcnt[i] = 0;
    __syncthreads();
    int e0 = blockIdx.x * chunk;
    int e1 = min(e0 + chunk, E);
    for (int e = e0 + threadIdx.x; e < e1; e += blockDim.x)
        atomicAdd(&lcnt[dst[e] >> 8], 1);
    __syncthreads();
    for (int b = threadIdx.x; b < NBK; b += blockDim.x)
        gcounts[blockIdx.x * NBK + b] = lcnt[b];
}

// per-bucket totals: btot[b] = sum_c gcounts[c*NBK+b]
__global__ void k_colsum(const int* __restrict__ gcounts, int* __restrict__ btot,
                         int NBK, int NCH) {
    __shared__ int lds[256];
    int b = blockIdx.x, t = threadIdx.x;
    int s = 0;
    for (int c = t; c < NCH; c += 256) s += gcounts[c * NBK + b];
    lds[t] = s;
    __syncthreads();
    for (int off = 128; off; off >>= 1) {
        if (t < off) lds[t] += lds[t + off];
        __syncthreads();
    }
    if (t == 0) btot[b] = lds[0];
}

// single block: bucket_base = exclusive scan of btot; zero-init red copies
__global__ void k_scanA(const int* __restrict__ btot, int* __restrict__ bucket_base,
                        float* __restrict__ red, int NBK) {
    __shared__ int lds[MAXB];
    int t = threadIdx.x;
    for (int i = t; i < RCOPY * 64; i += MAXB) red[i] = 0.f;
    int v = (t < NBK) ? btot[t] : 0;
    lds[t] = v;
    __syncthreads();
    for (int off = 1; off < MAXB; off <<= 1) {
        int add = (t >= off) ? lds[t - off] : 0;
        __syncthreads();
        lds[t] += add;
        __syncthreads();
    }
    if (t < NBK) bucket_base[t] = lds[t] - v;
    if (t == NBK - 1) bucket_base[NBK] = lds[t];
}

// per bucket: exclusive scan of gcounts[c*NBK+b] over c, in place
__global__ void k_scanB(int* __restrict__ gcounts, const int* __restrict__ bucket_base,
                        int NBK, int NCH) {
    __shared__ int lds[512];
    int b = blockIdx.x, t = threadIdx.x;
    int carry = bucket_base[b];
    for (int base = 0; base < NCH; base += 512) {
        int c = base + t;
        int v = (c < NCH) ? gcounts[c * NBK + b] : 0;
        lds[t] = v;
        __syncthreads();
        for (int off = 1; off < 512; off <<= 1) {
            int add = (t >= off) ? lds[t - off] : 0;
            __syncthreads();
            lds[t] += add;
            __syncthreads();
        }
        if (c < NCH) gcounts[c * NBK + b] = carry + lds[t] - v;
        int tot = lds[511];
        __syncthreads();
        carry += tot;
    }
}

// scatter packed records (local_d<<17 | src) into bucket-grouped order
__global__ void k_bucketize(const int* __restrict__ src, const int* __restrict__ dst,
                            int E, int chunk, const int* __restrict__ gcounts,
                            int* __restrict__ records, int NBK) {
    __shared__ int lcur[MAXB];
    for (int b = threadIdx.x; b < NBK; b += blockDim.x)
        lcur[b] = gcounts[blockIdx.x * NBK + b];
    __syncthreads();
    int e0 = blockIdx.x * chunk;
    int e1 = min(e0 + chunk, E);
    for (int e = e0 + threadIdx.x; e < e1; e += blockDim.x) {
        int d = dst[e];
        int b = d >> 8;
        int rec = ((d & 255) << 17) | src[e];
        int slot = atomicAdd(&lcur[b], 1);
        records[slot] = rec;
    }
}

// csrA: per-(bucket, slice) histogram of local nodes -> qhist
__global__ void k_csrA(const int* __restrict__ records, const int* __restrict__ bucket_base,
                       int* __restrict__ qhist) {
    __shared__ int cnt[BUCKET];
    int t = threadIdx.x, b = blockIdx.x, q = blockIdx.y;
    if (t < BUCKET) cnt[t] = 0;
    __syncthreads();
    int j0 = bucket_base[b], j1 = bucket_base[b + 1];
    int qlen = (j1 - j0 + Q - 1) / Q;
    int qs = j0 + q * qlen;
    int qe = min(qs + qlen, j1);
    for (int j = qs + t; j < qe; j += blockDim.x)
        atomicAdd(&cnt[records[j] >> 17], 1);
    __syncthreads();
    if (t < BUCKET) qhist[(b * Q + q) * BUCKET + t] = cnt[t];
}

// csrB: per-bucket scan of summed slice histograms -> pos/rowend/dinv/xs/degb,
// per-slice cursor bases qbase, per-block gf partials (no hot atomics)
__global__ void k_csrB(const int* __restrict__ qhist, const int* __restrict__ bucket_base,
                       const float* __restrict__ x,
                       int* __restrict__ qbase, int* __restrict__ pos,
                       int* __restrict__ rowend, float* __restrict__ dinv,
                       float* __restrict__ xs, float* __restrict__ gfpart,
                       unsigned char* __restrict__ degb, int n) {
    __shared__ int lds[BUCKET];
    __shared__ float gf6[8];
    int t = threadIdx.x, b = blockIdx.x;
    if (t < 8) gf6[t] = 0.f;
    int h[Q];
    int c = 0;
#pragma unroll
    for (int q = 0; q < Q; ++q) {
        h[q] = qhist[(b * Q + q) * BUCKET + t];
        c += h[q];
    }
    lds[t] = c;
    __syncthreads();
    for (int off = 1; off < BUCKET; off <<= 1) {
        int add = (t >= off) ? lds[t - off] : 0;
        __syncthreads();
        lds[t] += add;
        __syncthreads();
    }
    int j0 = bucket_base[b];
    int p = j0 + lds[t] - c;   // exclusive: row start for node (b,t)
    int run = p;
#pragma unroll
    for (int q = 0; q < Q; ++q) {
        qbase[(b * Q + q) * BUCKET + t] = run;
        run += h[q];
    }
    int node = b * BUCKET + t;
    float s2 = 0.f, s3 = 0.f, s4 = 0.f, sm0 = 0.f, sm1 = 0.f, sc = 0.f;
    if (node < n) {
        pos[node] = p;
        rowend[node] = p + c;
        degb[node] = (unsigned char)(c < 255 ? c : 255);
        float d = rsqrtf((float)(c + 1));
        dinv[node] = d;
        float x0 = x[node * 5 + 0], x1 = x[node * 5 + 1], x2 = x[node * 5 + 2];
        float x3 = x[node * 5 + 3], x4 = x[node * 5 + 4];
        float4 o;
        o.x = x0 * d; o.y = x1 * d; o.z = x2 * d; o.w = x3 * d;
        ((float4*)xs)[node * 2] = o;
        xs[node * 8 + 4] = x4 * d;
        s2 = x2; s3 = x3; s4 = x4;
        if (x2 == 1.0f) { sm0 = x0; sm1 = x1; sc = 1.f; }
    }
#pragma unroll
    for (int off = 32; off; off >>= 1) {
        s2 += __shfl_down(s2, off);
        s3 += __shfl_down(s3, off);
        s4 += __shfl_down(s4, off);
        sm0 += __shfl_down(sm0, off);
        sm1 += __shfl_down(sm1, off);
        sc += __shfl_down(sc, off);
    }
    if ((t & 63) == 0) {            // 4 waves -> LDS accumulate (cheap)
        atomicAdd(&gf6[0], s2);
        atomicAdd(&gf6[1], s3);
        atomicAdd(&gf6[2], s4);
        atomicAdd(&gf6[3], sm0);
        atomicAdd(&gf6[4], sm1);
        atomicAdd(&gf6[5], sc);
    }
    __syncthreads();
    if (t < 6) gfpart[b * 8 + t] = gf6[t];
}

// csrC: per-(bucket, slice) scatter into per-node CSR using private cursors
__global__ void k_csrC(const int* __restrict__ records, const int* __restrict__ bucket_base,
                       const int* __restrict__ qbase, int* __restrict__ ssrc) {
    __shared__ int cursor[BUCKET];
    int t = threadIdx.x, b = blockIdx.x, q = blockIdx.y;
    if (t < BUCKET) cursor[t] = qbase[(b * Q + q) * BUCKET + t];
    __syncthreads();
    int j0 = bucket_base[b], j1 = bucket_base[b + 1];
    int qlen = (j1 - j0 + Q - 1) / Q;
    int qs = j0 + q * qlen;
    int qe = min(qs + qlen, j1);
    for (int j = qs + t; j < qe; j += blockDim.x) {
        int rec = records[j];
        int slot = atomicAdd(&cursor[rec >> 17], 1);
        ssrc[slot] = rec & 131071;
    }
}

// degree counting sort, pass 1: per-block degree histograms
__global__ void k_dhist(const unsigned char* __restrict__ degb, int n,
                        int* __restrict__ dpart) {
    __shared__ int bins[256];
    int t = threadIdx.x, b = blockIdx.x;
    bins[t] = 0;
    __syncthreads();
    int chunk = (n + DNB - 1) / DNB;
    int i0 = b * chunk, i1 = min(i0 + chunk, n);
    for (int i = i0 + t; i < i1; i += 256)
        atomicAdd(&bins[degb[i]], 1);
    __syncthreads();
    dpart[b * 256 + t] = bins[t];
}

// pass 2 (1 block): bin totals -> exclusive scan -> per-(block,bin) bases
__global__ void k_dscan(int* __restrict__ dpart) {
    __shared__ int lds[256];
    int t = threadIdx.x;        // t = bin
    int tot = 0;
    for (int b = 0; b < DNB; ++b) tot += dpart[b * 256 + t];
    lds[t] = tot;
    __syncthreads();
    for (int off = 1; off < 256; off <<= 1) {
        int add = (t >= off) ? lds[t - off] : 0;
        __syncthreads();
        lds[t] += add;
        __syncthreads();
    }
    int run = lds[t] - tot;     // exclusive base of bin t
    for (int b = 0; b < DNB; ++b) {
        int v = dpart[b * 256 + t];
        dpart[b * 256 + t] = run;
        run += v;
    }
}

// pass 3: scatter node ids into degree-sorted perm
__global__ void k_dscatter(const unsigned char* __restrict__ degb,
                           const int* __restrict__ dpart, int n,
                           int* __restrict__ perm) {
    __shared__ int cur[256];
    int t = threadIdx.x, b = blockIdx.x;
    cur[t] = dpart[b * 256 + t];
    __syncthreads();
    int chunk = (n + DNB - 1) / DNB;
    int i0 = b * chunk, i1 = min(i0 + chunk, n);
    for (int i = i0 + t; i < i1; i += 256) {
        int slot = atomicAdd(&cur[degb[i]], 1);
        perm[slot] = i;
    }
}

// 5-dim aggregation in degree-sorted order (lanes in a wave have ~equal degree)
__global__ void k_agg5(const int* __restrict__ perm,
                       const int* __restrict__ pos, const int* __restrict__ rowend,
                       const int* __restrict__ ssrc, const float* __restrict__ dinv,
                       const float* __restrict__ xs, float* __restrict__ agg5, int n) {
    int gid = blockIdx.x * blockDim.x + threadIdx.x;
    if (gid >= n) return;
    int i = perm[gid];
    const float4* xs4 = (const float4*)xs;
    float4 a = xs4[i * 2];            // self term
    float a4 = xs[i * 8 + 4];
    int beg = pos[i], end = rowend[i];
    int j = beg;
    for (; j + 1 < end; j += 2) {
        int s0 = ssrc[j], s1 = ssrc[j + 1];
        float4 v0 = xs4[s0 * 2]; float w0 = xs[s0 * 8 + 4];
        float4 v1 = xs4[s1 * 2]; float w1 = xs[s1 * 8 + 4];
        a.x += v0.x + v1.x; a.y += v0.y + v1.y;
        a.z += v0.z + v1.z; a.w += v0.w + v1.w;
        a4 += w0 + w1;
    }
    for (; j < end; ++j) {
        int s = ssrc[j];
        float4 v = xs4[s * 2];
        a.x += v.x; a.y += v.y; a.z += v.z; a.w += v.w;
        a4 += xs[s * 8 + 4];
    }
    float dd = dinv[i];
    float4 o; o.x = a.x * dd; o.y = a.y * dd; o.z = a.z * dd; o.w = a.w * dd;
    ((float4*)agg5)[i * 2] = o;
    agg5[i * 8 + 4] = a4 * dd;
}

// h1s[i,f] = bf16( dinv[i] * relu( agg5[i,:] @ W1[:,f] + b1[f] ) )  (wave/node)
__global__ void k_h1(const float* __restrict__ agg5, const float* __restrict__ W1,
                     const float* __restrict__ b1, const float* __restrict__ dinv,
                     __hip_bfloat16* __restrict__ h1s, int n) {
    int t = blockIdx.x * blockDim.x + threadIdx.x;
    int i = t >> 6, f = t & 63;
    if (i >= n) return;
    float a0 = agg5[i * 8 + 0], a1 = agg5[i * 8 + 1], a2 = agg5[i * 8 + 2];
    float a3 = agg5[i * 8 + 3], a4 = agg5[i * 8 + 4];
    float v = a0 * W1[f] + a1 * W1[64 + f] + a2 * W1[128 + f]
            + a3 * W1[192 + f] + a4 * W1[256 + f] + b1[f];
    h1s[(size_t)i * 64 + f] = __float2bfloat16(dinv[i] * fmaxf(v, 0.f));
}

// Layer 2 fully fused: 8 degree-matched streams per wave, W2 in 64 VGPRs,
// shfl matmul with dual accumulators, RCOPY-spread mean-pool accumulation.
__global__ __launch_bounds__(256)
void k_l2fuse(const int* __restrict__ perm,
              const int* __restrict__ pos, const int* __restrict__ rowend,
              const int* __restrict__ ssrc, const float* __restrict__ dinv,
              const __hip_bfloat16* __restrict__ h1s, const float* __restrict__ W2,
              const float* __restrict__ b2, float* __restrict__ red, int n) {
    __shared__ float red64[64];
    int t = threadIdx.x, f = t & 63;
    if (t < 64) red64[t] = 0.f;
    __syncthreads();
    float w2r[64];
#pragma unroll
    for (int k = 0; k < 64; ++k) w2r[k] = W2[k * 64 + f];
    float bf = b2[f];
    int w = blockIdx.x * (blockDim.x >> 6) + (t >> 6);
    int nw = gridDim.x * (blockDim.x >> 6);
    float psum = 0.f;
    int nt = (n + 7) >> 3;
    for (int task = w; task < nt; task += nw) {
        int base = task * 8;
#define SI(q) \
        int i##q = (base + q < n) ? perm[base + q] : -1; \
        bool v##q = i##q >= 0; \
        int p##q = v##q ? pos[i##q] : 0; \
        int e##q = v##q ? rowend[i##q] : 0; \
        float a##q = v##q ? __bfloat162float(h1s[(size_t)i##q * 64 + f]) : 0.f;
        SI(0) SI(1) SI(2) SI(3) SI(4) SI(5) SI(6) SI(7)
#undef SI
        int len = max(max(max(e0 - p0, e1 - p1), max(e2 - p2, e3 - p3)),
                      max(max(e4 - p4, e5 - p5), max(e6 - p6, e7 - p7)));
#pragma unroll 2
        for (int m = 0; m < len; ++m) {
#define SS(q) \
            { int j = p##q + m; \
              int s = ssrc[j < e##q ? j : 0]; \
              float g = __bfloat162float(h1s[(size_t)s * 64 + f]); \
              if (j < e##q) a##q += g; }
            SS(0) SS(1) SS(2) SS(3) SS(4) SS(5) SS(6) SS(7)
#undef SS
        }
#define SMM(q) { \
        float qa = 0.f, qb = 0.f; \
        _Pragma("unroll") \
        for (int k = 0; k < 64; k += 2) { \
            qa += __shfl(a##q, k) * w2r[k]; \
            qb += __shfl(a##q, k + 1) * w2r[k + 1]; \
        } \
        if (v##q) psum += fmaxf((qa + qb) * dinv[i##q] + bf, 0.f); }
        SMM(0) SMM(1) SMM(2) SMM(3) SMM(4) SMM(5) SMM(6) SMM(7)
#undef SMM
    }
    atomicAdd(&red64[f], psum);
    __syncthreads();
    if (t < 64) atomicAdd(&red[(blockIdx.x & (RCOPY - 1)) * 64 + t], red64[t]);
}

// Final head: emb = [mean(h2), gf(6)] (70), MLP 70->32->2, 2+3*sigmoid.
__global__ void k_head(const float* __restrict__ red, const float* __restrict__ gfpart,
                       const float* __restrict__ l1w, const float* __restrict__ l1b,
                       const float* __restrict__ l2w, const float* __restrict__ l2b,
                       float* __restrict__ out, int n, int NBK) {
    __shared__ float emb[70];
    __shared__ float hid[32];
    int t = threadIdx.x;
    if (t < 64) {
        float s = 0.f;
#pragma unroll
        for (int c = 0; c < RCOPY; ++c) s += red[c * 64 + t];
        emb[t] = s / (float)n;
    }
    float g0 = 0.f, g1 = 0.f, g2 = 0.f, g3 = 0.f, g4 = 0.f, g5 = 0.f;
    for (int b = t; b < NBK; b += 64) {
        g0 += gfpart[b * 8 + 0]; g1 += gfpart[b * 8 + 1];
        g2 += gfpart[b * 8 + 2]; g3 += gfpart[b * 8 + 3];
        g4 += gfpart[b * 8 + 4]; g5 += gfpart[b * 8 + 5];
    }
#pragma unroll
    for (int off = 32; off; off >>= 1) {
        g0 += __shfl_down(g0, off); g1 += __shfl_down(g1, off);
        g2 += __shfl_down(g2, off); g3 += __shfl_down(g3, off);
        g4 += __shfl_down(g4, off); g5 += __shfl_down(g5, off);
    }
    if (t == 0) {
        float cnt = g5;
        float safe = fmaxf(cnt, 1.f);
        emb[64] = g0;                       // n_comp
        emb[65] = g1;                       // n_and
        emb[66] = g2;                       // n_or
        emb[67] = g1 + g2;                  // depth
        emb[68] = cnt > 0.f ? g3 / safe : 0.f;   // avg_lambda
        emb[69] = cnt > 0.f ? g4 / safe : 0.f;   // avg_mu
    }
    __syncthreads();
    if (t < 32) {
        float acc = l1b[t];
#pragma unroll
        for (int k = 0; k < 70; ++k) acc += emb[k] * l1w[k * 32 + t];
        hid[t] = fmaxf(acc, 0.f);
    }
    __syncthreads();
    if (t < 2) {
        float acc = l2b[t];
#pragma unroll
        for (int j = 0; j < 32; ++j) acc += hid[j] * l2w[j * 2 + t];
        out[t] = 2.0f + 3.0f / (1.0f + expf(-acc));
    }
}

extern "C" void kernel_launch(void* const* d_in, const int* in_sizes, int n_in,
                              void* d_out, int out_size, void* d_ws, size_t ws_size,
                              hipStream_t stream) {
    const float* x   = (const float*)d_in[0];
    const int*   ei  = (const int*)d_in[1];
    const float* w1  = (const float*)d_in[2];
    const float* b1  = (const float*)d_in[3];
    const float* w2  = (const float*)d_in[4];
    const float* b2  = (const float*)d_in[5];
    const float* l1w = (const float*)d_in[6];
    const float* l1b = (const float*)d_in[7];
    const float* l2w = (const float*)d_in[8];
    const float* l2b = (const float*)d_in[9];

    const int n = in_sizes[0] / 5;
    const int E = in_sizes[1] / 2;
    const int* src = ei;
    const int* dst = ei + E;

    const int NBK = (n + BUCKET - 1) / BUCKET;   // 391 buckets
    const int NCH = NCHV;                         // 2048 edge chunks
    const int chunk = (E + NCH - 1) / NCH;

    size_t nf = (size_t)n * 64;
    __hip_bfloat16* h1s = (__hip_bfloat16*)d_ws;      // N x 64 bf16 prescaled
    float* xs          = (float*)(h1s + nf);          // N x 8 (padded)
    float* agg5        = xs + (size_t)n * 8;          // N x 8 (padded)
    float* dinv        = agg5 + (size_t)n * 8;
    float* red         = dinv + n;                    // RCOPY*64 floats
    float* gfpart      = red + RCOPY * 64;            // NBK*8 floats
    int*   pos         = (int*)(gfpart + (MAXB * 8));
    int*   rowend      = pos + n;
    int*   btot        = rowend + n;                  // MAXB ints
    int*   bucket_base = btot + MAXB;                 // NBK+1
    int*   qhist       = bucket_base + (MAXB + 8);    // NBK*Q*256
    int*   qbase       = qhist + NBK * Q * BUCKET;    // NBK*Q*256
    int*   perm        = qbase + NBK * Q * BUCKET;    // n ints
    int*   dpart       = perm + n;                    // DNB*256 ints
    unsigned char* degb = (unsigned char*)(dpart + DNB * 256);  // n bytes
    int*   gcounts     = (int*)(degb + ((n + 15) & ~15));       // NCH*NBK
    int*   records     = gcounts + NCH * NBK;         // E ints
    int*   ssrc        = records + E;                 // E ints, per-node CSR

    k_hist<<<NCH, 512, 0, stream>>>(dst, E, chunk, gcounts, NBK);
    k_colsum<<<NBK, 256, 0, stream>>>(gcounts, btot, NBK, NCH);
    k_scanA<<<1, MAXB, 0, stream>>>(btot, bucket_base, red, NBK);
    k_scanB<<<NBK, 512, 0, stream>>>(gcounts, bucket_base, NBK, NCH);
    k_bucketize<<<NCH, 512, 0, stream>>>(src, dst, E, chunk, gcounts, records, NBK);

    dim3 qgrid(NBK, Q);
    k_csrA<<<qgrid, 512, 0, stream>>>(records, bucket_base, qhist);
    k_csrB<<<NBK, BUCKET, 0, stream>>>(qhist, bucket_base, x, qbase, pos, rowend,
                                       dinv, xs, gfpart, degb, n);
    k_csrC<<<qgrid, 512, 0, stream>>>(records, bucket_base, qbase, ssrc);

    k_dhist<<<DNB, 256, 0, stream>>>(degb, n, dpart);
    k_dscan<<<1, 256, 0, stream>>>(dpart);
    k_dscatter<<<DNB, 256, 0, stream>>>(degb, dpart, n, perm);

    k_agg5<<<(n + 255) / 256, 256, 0, stream>>>(perm, pos, rowend, ssrc, dinv, xs, agg5, n);
    k_h1<<<(int)((nf + 255) / 256), 256, 0, stream>>>(agg5, w1, b1, dinv, h1s, n);

    const int nt = (n + 7) >> 3;
    const int l2blocks = (nt + 3) / 4;               // 1 task per wave
    k_l2fuse<<<l2blocks, 256, 0, stream>>>(perm, pos, rowend, ssrc, dinv, h1s,
                                           w2, b2, red, n);

    k_head<<<1, 64, 0, stream>>>(red, gfpart, l1w, l1b, l2w, l2b, (float*)d_out, n, NBK);
}

// Round 14
// 292.466 us; speedup vs baseline: 1.2991x; 1.2991x over previous
//
#include <hip/hip_runtime.h>
#include <hip/hip_bf16.h>
#include <math.h>

// ---------------------------------------------------------------------------
// GCN predictor: 2x GCNConv(relu) -> mean pool + global feats -> MLP head
// N=100K nodes, E=3.2M directed edges, H=64.
// R14: degree-sorted streams kept, but l2fuse reverted to R12's 4-stream /
// low-VGPR structure (R13's W2-VGPR hoist + 8 streams collapsed occupancy
// 65%->20%). agg5 writes coalesced in sorted layout (agg5s[gid]); h1 maps
// back via perm. No hot-address atomics (R12 discipline).
// ---------------------------------------------------------------------------

#define BUCKET 256
#define MAXB   512    // max buckets (needs n <= 131072)
#define NCHV   2048   // edge chunks
#define Q      8      // csr record slices per bucket
#define RCOPY  32     // spread copies for the mean-pool accumulator
#define DNB    256    // degree-sort blocks

// per-chunk bucket histogram: gcounts[chunk*NBK + bucket]
__global__ void k_hist(const int* __restrict__ dst, int E, int chunk,
                       int* __restrict__ gcounts, int NBK) {
    __shared__ int lcnt[MAXB];
    for (int i = threadIdx.x; i < NBK; i += blockDim.x) lcnt[i] = 0;
    __syncthreads();
    int e0 = blockIdx.x * chunk;
    int e1 = min(e0 + chunk, E);
    for (int e = e0 + threadIdx.x; e < e1; e += blockDim.x)
        atomicAdd(&lcnt[dst[e] >> 8], 1);
    __syncthreads();
    for (int b = threadIdx.x; b < NBK; b += blockDim.x)
        gcounts[blockIdx.x * NBK + b] = lcnt[b];
}

// per-bucket totals: btot[b] = sum_c gcounts[c*NBK+b]
__global__ void k_colsum(const int* __restrict__ gcounts, int* __restrict__ btot,
                         int NBK, int NCH) {
    __shared__ int lds[256];
    int b = blockIdx.x, t = threadIdx.x;
    int s = 0;
    for (int c = t; c < NCH; c += 256) s += gcounts[c * NBK + b];
    lds[t] = s;
    __syncthreads();
    for (int off = 128; off; off >>= 1) {
        if (t < off) lds[t] += lds[t + off];
        __syncthreads();
    }
    if (t == 0) btot[b] = lds[0];
}

// single block: bucket_base = exclusive scan of btot; zero-init red copies
__global__ void k_scanA(const int* __restrict__ btot, int* __restrict__ bucket_base,
                        float* __restrict__ red, int NBK) {
    __shared__ int lds[MAXB];
    int t = threadIdx.x;
    for (int i = t; i < RCOPY * 64; i += MAXB) red[i] = 0.f;
    int v = (t < NBK) ? btot[t] : 0;
    lds[t] = v;
    __syncthreads();
    for (int off = 1; off < MAXB; off <<= 1) {
        int add = (t >= off) ? lds[t - off] : 0;
        __syncthreads();
        lds[t] += add;
        __syncthreads();
    }
    if (t < NBK) bucket_base[t] = lds[t] - v;
    if (t == NBK - 1) bucket_base[NBK] = lds[t];
}

// per bucket: exclusive scan of gcounts[c*NBK+b] over c, in place
__global__ void k_scanB(int* __restrict__ gcounts, const int* __restrict__ bucket_base,
                        int NBK, int NCH) {
    __shared__ int lds[512];
    int b = blockIdx.x, t = threadIdx.x;
    int carry = bucket_base[b];
    for (int base = 0; base < NCH; base += 512) {
        int c = base + t;
        int v = (c < NCH) ? gcounts[c * NBK + b] : 0;
        lds[t] = v;
        __syncthreads();
        for (int off = 1; off < 512; off <<= 1) {
            int add = (t >= off) ? lds[t - off] : 0;
            __syncthreads();
            lds[t] += add;
            __syncthreads();
        }
        if (c < NCH) gcounts[c * NBK + b] = carry + lds[t] - v;
        int tot = lds[511];
        __syncthreads();
        carry += tot;
    }
}

// scatter packed records (local_d<<17 | src) into bucket-grouped order
__global__ void k_bucketize(const int* __restrict__ src, const int* __restrict__ dst,
                            int E, int chunk, const int* __restrict__ gcounts,
                            int* __restrict__ records, int NBK) {
    __shared__ int lcur[MAXB];
    for (int b = threadIdx.x; b < NBK; b += blockDim.x)
        lcur[b] = gcounts[blockIdx.x * NBK + b];
    __syncthreads();
    int e0 = blockIdx.x * chunk;
    int e1 = min(e0 + chunk, E);
    for (int e = e0 + threadIdx.x; e < e1; e += blockDim.x) {
        int d = dst[e];
        int b = d >> 8;
        int rec = ((d & 255) << 17) | src[e];
        int slot = atomicAdd(&lcur[b], 1);
        records[slot] = rec;
    }
}

// csrA: per-(bucket, slice) histogram of local nodes -> qhist
__global__ void k_csrA(const int* __restrict__ records, const int* __restrict__ bucket_base,
                       int* __restrict__ qhist) {
    __shared__ int cnt[BUCKET];
    int t = threadIdx.x, b = blockIdx.x, q = blockIdx.y;
    if (t < BUCKET) cnt[t] = 0;
    __syncthreads();
    int j0 = bucket_base[b], j1 = bucket_base[b + 1];
    int qlen = (j1 - j0 + Q - 1) / Q;
    int qs = j0 + q * qlen;
    int qe = min(qs + qlen, j1);
    for (int j = qs + t; j < qe; j += blockDim.x)
        atomicAdd(&cnt[records[j] >> 17], 1);
    __syncthreads();
    if (t < BUCKET) qhist[(b * Q + q) * BUCKET + t] = cnt[t];
}

// csrB: per-bucket scan of summed slice histograms -> pos/rowend/dinv/xs/degb,
// per-slice cursor bases qbase, per-block gf partials (no hot atomics)
__global__ void k_csrB(const int* __restrict__ qhist, const int* __restrict__ bucket_base,
                       const float* __restrict__ x,
                       int* __restrict__ qbase, int* __restrict__ pos,
                       int* __restrict__ rowend, float* __restrict__ dinv,
                       float* __restrict__ xs, float* __restrict__ gfpart,
                       unsigned char* __restrict__ degb, int n) {
    __shared__ int lds[BUCKET];
    __shared__ float gf6[8];
    int t = threadIdx.x, b = blockIdx.x;
    if (t < 8) gf6[t] = 0.f;
    int h[Q];
    int c = 0;
#pragma unroll
    for (int q = 0; q < Q; ++q) {
        h[q] = qhist[(b * Q + q) * BUCKET + t];
        c += h[q];
    }
    lds[t] = c;
    __syncthreads();
    for (int off = 1; off < BUCKET; off <<= 1) {
        int add = (t >= off) ? lds[t - off] : 0;
        __syncthreads();
        lds[t] += add;
        __syncthreads();
    }
    int j0 = bucket_base[b];
    int p = j0 + lds[t] - c;   // exclusive: row start for node (b,t)
    int run = p;
#pragma unroll
    for (int q = 0; q < Q; ++q) {
        qbase[(b * Q + q) * BUCKET + t] = run;
        run += h[q];
    }
    int node = b * BUCKET + t;
    float s2 = 0.f, s3 = 0.f, s4 = 0.f, sm0 = 0.f, sm1 = 0.f, sc = 0.f;
    if (node < n) {
        pos[node] = p;
        rowend[node] = p + c;
        degb[node] = (unsigned char)(c < 255 ? c : 255);
        float d = rsqrtf((float)(c + 1));
        dinv[node] = d;
        float x0 = x[node * 5 + 0], x1 = x[node * 5 + 1], x2 = x[node * 5 + 2];
        float x3 = x[node * 5 + 3], x4 = x[node * 5 + 4];
        float4 o;
        o.x = x0 * d; o.y = x1 * d; o.z = x2 * d; o.w = x3 * d;
        ((float4*)xs)[node * 2] = o;
        xs[node * 8 + 4] = x4 * d;
        s2 = x2; s3 = x3; s4 = x4;
        if (x2 == 1.0f) { sm0 = x0; sm1 = x1; sc = 1.f; }
    }
#pragma unroll
    for (int off = 32; off; off >>= 1) {
        s2 += __shfl_down(s2, off);
        s3 += __shfl_down(s3, off);
        s4 += __shfl_down(s4, off);
        sm0 += __shfl_down(sm0, off);
        sm1 += __shfl_down(sm1, off);
        sc += __shfl_down(sc, off);
    }
    if ((t & 63) == 0) {            // 4 waves -> LDS accumulate (cheap)
        atomicAdd(&gf6[0], s2);
        atomicAdd(&gf6[1], s3);
        atomicAdd(&gf6[2], s4);
        atomicAdd(&gf6[3], sm0);
        atomicAdd(&gf6[4], sm1);
        atomicAdd(&gf6[5], sc);
    }
    __syncthreads();
    if (t < 6) gfpart[b * 8 + t] = gf6[t];
}

// csrC: per-(bucket, slice) scatter into per-node CSR using private cursors
__global__ void k_csrC(const int* __restrict__ records, const int* __restrict__ bucket_base,
                       const int* __restrict__ qbase, int* __restrict__ ssrc) {
    __shared__ int cursor[BUCKET];
    int t = threadIdx.x, b = blockIdx.x, q = blockIdx.y;
    if (t < BUCKET) cursor[t] = qbase[(b * Q + q) * BUCKET + t];
    __syncthreads();
    int j0 = bucket_base[b], j1 = bucket_base[b + 1];
    int qlen = (j1 - j0 + Q - 1) / Q;
    int qs = j0 + q * qlen;
    int qe = min(qs + qlen, j1);
    for (int j = qs + t; j < qe; j += blockDim.x) {
        int rec = records[j];
        int slot = atomicAdd(&cursor[rec >> 17], 1);
        ssrc[slot] = rec & 131071;
    }
}

// degree counting sort, pass 1: per-block degree histograms
__global__ void k_dhist(const unsigned char* __restrict__ degb, int n,
                        int* __restrict__ dpart) {
    __shared__ int bins[256];
    int t = threadIdx.x, b = blockIdx.x;
    bins[t] = 0;
    __syncthreads();
    int chunk = (n + DNB - 1) / DNB;
    int i0 = b * chunk, i1 = min(i0 + chunk, n);
    for (int i = i0 + t; i < i1; i += 256)
        atomicAdd(&bins[degb[i]], 1);
    __syncthreads();
    dpart[b * 256 + t] = bins[t];
}

// pass 2 (1 block): bin totals -> exclusive scan -> per-(block,bin) bases
__global__ void k_dscan(int* __restrict__ dpart) {
    __shared__ int lds[256];
    int t = threadIdx.x;        // t = bin
    int tot = 0;
    for (int b = 0; b < DNB; ++b) tot += dpart[b * 256 + t];
    lds[t] = tot;
    __syncthreads();
    for (int off = 1; off < 256; off <<= 1) {
        int add = (t >= off) ? lds[t - off] : 0;
        __syncthreads();
        lds[t] += add;
        __syncthreads();
    }
    int run = lds[t] - tot;     // exclusive base of bin t
    for (int b = 0; b < DNB; ++b) {
        int v = dpart[b * 256 + t];
        dpart[b * 256 + t] = run;
        run += v;
    }
}

// pass 3: scatter node ids into degree-sorted perm
__global__ void k_dscatter(const unsigned char* __restrict__ degb,
                           const int* __restrict__ dpart, int n,
                           int* __restrict__ perm) {
    __shared__ int cur[256];
    int t = threadIdx.x, b = blockIdx.x;
    cur[t] = dpart[b * 256 + t];
    __syncthreads();
    int chunk = (n + DNB - 1) / DNB;
    int i0 = b * chunk, i1 = min(i0 + chunk, n);
    for (int i = i0 + t; i < i1; i += 256) {
        int slot = atomicAdd(&cur[degb[i]], 1);
        perm[slot] = i;
    }
}

// 5-dim aggregation in degree-sorted order; OUTPUT IN SORTED LAYOUT (agg5s[gid])
// so writes stay coalesced. Self/neighbor xs reads are L2-resident gathers.
__global__ void k_agg5(const int* __restrict__ perm,
                       const int* __restrict__ pos, const int* __restrict__ rowend,
                       const int* __restrict__ ssrc, const float* __restrict__ dinv,
                       const float* __restrict__ xs, float* __restrict__ agg5s, int n) {
    int gid = blockIdx.x * blockDim.x + threadIdx.x;
    if (gid >= n) return;
    int i = perm[gid];
    const float4* xs4 = (const float4*)xs;
    float4 a = xs4[i * 2];            // self term
    float a4 = xs[i * 8 + 4];
    int beg = pos[i], end = rowend[i];
    int j = beg;
    for (; j + 1 < end; j += 2) {
        int s0 = ssrc[j], s1 = ssrc[j + 1];
        float4 v0 = xs4[s0 * 2]; float w0 = xs[s0 * 8 + 4];
        float4 v1 = xs4[s1 * 2]; float w1 = xs[s1 * 8 + 4];
        a.x += v0.x + v1.x; a.y += v0.y + v1.y;
        a.z += v0.z + v1.z; a.w += v0.w + v1.w;
        a4 += w0 + w1;
    }
    for (; j < end; ++j) {
        int s = ssrc[j];
        float4 v = xs4[s * 2];
        a.x += v.x; a.y += v.y; a.z += v.z; a.w += v.w;
        a4 += xs[s * 8 + 4];
    }
    float dd = dinv[i];
    float4 o; o.x = a.x * dd; o.y = a.y * dd; o.z = a.z * dd; o.w = a.w * dd;
    ((float4*)agg5s)[gid * 2] = o;
    agg5s[gid * 8 + 4] = a4 * dd;
}

// h1s[perm[gid],f] = bf16( dinv * relu( agg5s[gid,:] @ W1[:,f] + b1[f] ) )
// agg5s read coalesced; h1s write is one contiguous 128B row per wave.
__global__ void k_h1(const int* __restrict__ perm, const float* __restrict__ agg5s,
                     const float* __restrict__ W1, const float* __restrict__ b1,
                     const float* __restrict__ dinv, __hip_bfloat16* __restrict__ h1s,
                     int n) {
    int t = blockIdx.x * blockDim.x + threadIdx.x;
    int gid = t >> 6, f = t & 63;
    if (gid >= n) return;
    int i = perm[gid];
    float a0 = agg5s[gid * 8 + 0], a1 = agg5s[gid * 8 + 1], a2 = agg5s[gid * 8 + 2];
    float a3 = agg5s[gid * 8 + 3], a4 = agg5s[gid * 8 + 4];
    float v = a0 * W1[f] + a1 * W1[64 + f] + a2 * W1[128 + f]
            + a3 * W1[192 + f] + a4 * W1[256 + f] + b1[f];
    h1s[(size_t)i * 64 + f] = __float2bfloat16(dinv[i] * fmaxf(v, 0.f));
}

// Layer 2 fully fused (R12 low-VGPR structure), 4 degree-matched streams/wave:
// gather bf16 h1s rows, shfl matmul (@W2 from L1), RCOPY-spread accumulation.
__global__ __launch_bounds__(256)
void k_l2fuse(const int* __restrict__ perm,
              const int* __restrict__ pos, const int* __restrict__ rowend,
              const int* __restrict__ ssrc, const float* __restrict__ dinv,
              const __hip_bfloat16* __restrict__ h1s, const float* __restrict__ W2,
              const float* __restrict__ b2, float* __restrict__ red, int n) {
    __shared__ float red64[64];
    int t = threadIdx.x, f = t & 63;
    if (t < 64) red64[t] = 0.f;
    __syncthreads();
    int w = blockIdx.x * (blockDim.x >> 6) + (t >> 6);
    int nw = gridDim.x * (blockDim.x >> 6);
    float bf = b2[f];
    float psum = 0.f;
    int nt = (n + 3) >> 2;
    for (int task = w; task < nt; task += nw) {
        int g0i = task * 4;
        int i0 = perm[g0i];                                  // g0i < n always
        bool v1 = g0i + 1 < n, v2 = g0i + 2 < n, v3 = g0i + 3 < n;
        int i1 = v1 ? perm[g0i + 1] : 0;
        int i2 = v2 ? perm[g0i + 2] : 0;
        int i3 = v3 ? perm[g0i + 3] : 0;
        int p0 = pos[i0],            e0 = rowend[i0];
        int p1 = v1 ? pos[i1] : 0,   e1 = v1 ? rowend[i1] : 0;
        int p2 = v2 ? pos[i2] : 0,   e2 = v2 ? rowend[i2] : 0;
        int p3 = v3 ? pos[i3] : 0,   e3 = v3 ? rowend[i3] : 0;
        float a0 = __bfloat162float(h1s[(size_t)i0 * 64 + f]);
        float a1 = v1 ? __bfloat162float(h1s[(size_t)i1 * 64 + f]) : 0.f;
        float a2 = v2 ? __bfloat162float(h1s[(size_t)i2 * 64 + f]) : 0.f;
        float a3 = v3 ? __bfloat162float(h1s[(size_t)i3 * 64 + f]) : 0.f;
        int len = max(max(e0 - p0, e1 - p1), max(e2 - p2, e3 - p3));
#pragma unroll 2
        for (int m = 0; m < len; ++m) {
            int j0 = p0 + m, j1 = p1 + m, j2 = p2 + m, j3 = p3 + m;
            int s0 = ssrc[j0 < e0 ? j0 : 0];
            int s1 = ssrc[j1 < e1 ? j1 : 0];
            int s2 = ssrc[j2 < e2 ? j2 : 0];
            int s3 = ssrc[j3 < e3 ? j3 : 0];
            float g0 = __bfloat162float(h1s[(size_t)s0 * 64 + f]);
            float g1 = __bfloat162float(h1s[(size_t)s1 * 64 + f]);
            float g2 = __bfloat162float(h1s[(size_t)s2 * 64 + f]);
            float g3 = __bfloat162float(h1s[(size_t)s3 * 64 + f]);
            if (j0 < e0) a0 += g0;
            if (j1 < e1) a1 += g1;
            if (j2 < e2) a2 += g2;
            if (j3 < e3) a3 += g3;
        }
        float q0 = 0.f, q1 = 0.f, q2 = 0.f, q3 = 0.f;
#pragma unroll 8
        for (int k = 0; k < 64; ++k) {
            float w2v = W2[k * 64 + f];
            q0 += __shfl(a0, k) * w2v;
            q1 += __shfl(a1, k) * w2v;
            q2 += __shfl(a2, k) * w2v;
            q3 += __shfl(a3, k) * w2v;
        }
        psum += fmaxf(q0 * dinv[i0] + bf, 0.f);
        if (v1) psum += fmaxf(q1 * dinv[i1] + bf, 0.f);
        if (v2) psum += fmaxf(q2 * dinv[i2] + bf, 0.f);
        if (v3) psum += fmaxf(q3 * dinv[i3] + bf, 0.f);
    }
    atomicAdd(&red64[f], psum);
    __syncthreads();
    if (t < 64) atomicAdd(&red[(blockIdx.x & (RCOPY - 1)) * 64 + t], red64[t]);
}

// Final head: emb = [mean(h2), gf(6)] (70), MLP 70->32->2, 2+3*sigmoid.
__global__ void k_head(const float* __restrict__ red, const float* __restrict__ gfpart,
                       const float* __restrict__ l1w, const float* __restrict__ l1b,
                       const float* __restrict__ l2w, const float* __restrict__ l2b,
                       float* __restrict__ out, int n, int NBK) {
    __shared__ float emb[70];
    __shared__ float hid[32];
    int t = threadIdx.x;
    if (t < 64) {
        float s = 0.f;
#pragma unroll
        for (int c = 0; c < RCOPY; ++c) s += red[c * 64 + t];
        emb[t] = s / (float)n;
    }
    float g0 = 0.f, g1 = 0.f, g2 = 0.f, g3 = 0.f, g4 = 0.f, g5 = 0.f;
    for (int b = t; b < NBK; b += 64) {
        g0 += gfpart[b * 8 + 0]; g1 += gfpart[b * 8 + 1];
        g2 += gfpart[b * 8 + 2]; g3 += gfpart[b * 8 + 3];
        g4 += gfpart[b * 8 + 4]; g5 += gfpart[b * 8 + 5];
    }
#pragma unroll
    for (int off = 32; off; off >>= 1) {
        g0 += __shfl_down(g0, off); g1 += __shfl_down(g1, off);
        g2 += __shfl_down(g2, off); g3 += __shfl_down(g3, off);
        g4 += __shfl_down(g4, off); g5 += __shfl_down(g5, off);
    }
    if (t == 0) {
        float cnt = g5;
        float safe = fmaxf(cnt, 1.f);
        emb[64] = g0;                       // n_comp
        emb[65] = g1;                       // n_and
        emb[66] = g2;                       // n_or
        emb[67] = g1 + g2;                  // depth
        emb[68] = cnt > 0.f ? g3 / safe : 0.f;   // avg_lambda
        emb[69] = cnt > 0.f ? g4 / safe : 0.f;   // avg_mu
    }
    __syncthreads();
    if (t < 32) {
        float acc = l1b[t];
#pragma unroll
        for (int k = 0; k < 70; ++k) acc += emb[k] * l1w[k * 32 + t];
        hid[t] = fmaxf(acc, 0.f);
    }
    __syncthreads();
    if (t < 2) {
        float acc = l2b[t];
#pragma unroll
        for (int j = 0; j < 32; ++j) acc += hid[j] * l2w[j * 2 + t];
        out[t] = 2.0f + 3.0f / (1.0f + expf(-acc));
    }
}

extern "C" void kernel_launch(void* const* d_in, const int* in_sizes, int n_in,
                              void* d_out, int out_size, void* d_ws, size_t ws_size,
                              hipStream_t stream) {
    const float* x   = (const float*)d_in[0];
    const int*   ei  = (const int*)d_in[1];
    const float* w1  = (const float*)d_in[2];
    const float* b1  = (const float*)d_in[3];
    const float* w2  = (const float*)d_in[4];
    const float* b2  = (const float*)d_in[5];
    const float* l1w = (const float*)d_in[6];
    const float* l1b = (const float*)d_in[7];
    const float* l2w = (const float*)d_in[8];
    const float* l2b = (const float*)d_in[9];

    const int n = in_sizes[0] / 5;
    const int E = in_sizes[1] / 2;
    const int* src = ei;
    const int* dst = ei + E;

    const int NBK = (n + BUCKET - 1) / BUCKET;   // 391 buckets
    const int NCH = NCHV;                         // 2048 edge chunks
    const int chunk = (E + NCH - 1) / NCH;

    size_t nf = (size_t)n * 64;
    __hip_bfloat16* h1s = (__hip_bfloat16*)d_ws;      // N x 64 bf16 prescaled
    float* xs          = (float*)(h1s + nf);          // N x 8 (padded)
    float* agg5s       = xs + (size_t)n * 8;          // N x 8 (sorted layout)
    float* dinv        = agg5s + (size_t)n * 8;
    float* red         = dinv + n;                    // RCOPY*64 floats
    float* gfpart      = red + RCOPY * 64;            // NBK*8 floats
    int*   pos         = (int*)(gfpart + (MAXB * 8));
    int*   rowend      = pos + n;
    int*   btot        = rowend + n;                  // MAXB ints
    int*   bucket_base = btot + MAXB;                 // NBK+1
    int*   qhist       = bucket_base + (MAXB + 8);    // NBK*Q*256
    int*   qbase       = qhist + NBK * Q * BUCKET;    // NBK*Q*256
    int*   perm        = qbase + NBK * Q * BUCKET;    // n ints
    int*   dpart       = perm + n;                    // DNB*256 ints
    unsigned char* degb = (unsigned char*)(dpart + DNB * 256);  // n bytes
    int*   gcounts     = (int*)(degb + ((n + 15) & ~15));       // NCH*NBK
    int*   records     = gcounts + NCH * NBK;         // E ints
    int*   ssrc        = records + E;                 // E ints, per-node CSR

    k_hist<<<NCH, 512, 0, stream>>>(dst, E, chunk, gcounts, NBK);
    k_colsum<<<NBK, 256, 0, stream>>>(gcounts, btot, NBK, NCH);
    k_scanA<<<1, MAXB, 0, stream>>>(btot, bucket_base, red, NBK);
    k_scanB<<<NBK, 512, 0, stream>>>(gcounts, bucket_base, NBK, NCH);
    k_bucketize<<<NCH, 512, 0, stream>>>(src, dst, E, chunk, gcounts, records, NBK);

    dim3 qgrid(NBK, Q);
    k_csrA<<<qgrid, 512, 0, stream>>>(records, bucket_base, qhist);
    k_csrB<<<NBK, BUCKET, 0, stream>>>(qhist, bucket_base, x, qbase, pos, rowend,
                                       dinv, xs, gfpart, degb, n);
    k_csrC<<<qgrid, 512, 0, stream>>>(records, bucket_base, qbase, ssrc);

    k_dhist<<<DNB, 256, 0, stream>>>(degb, n, dpart);
    k_dscan<<<1, 256, 0, stream>>>(dpart);
    k_dscatter<<<DNB, 256, 0, stream>>>(degb, dpart, n, perm);

    k_agg5<<<(n + 255) / 256, 256, 0, stream>>>(perm, pos, rowend, ssrc, dinv, xs, agg5s, n);
    k_h1<<<(int)((nf + 255) / 256), 256, 0, stream>>>(perm, agg5s, w1, b1, dinv, h1s, n);

    k_l2fuse<<<4096, 256, 0, stream>>>(perm, pos, rowend, ssrc, dinv, h1s, w2, b2, red, n);

    k_head<<<1, 64, 0, stream>>>(red, gfpart, l1w, l1b, l2w, l2b, (float*)d_out, n, NBK);
}